// Round 4
// baseline (366.149 us; speedup 1.0000x reference)
//
#include <hip/hip_runtime.h>
#include <hip/hip_bf16.h>

#define Bb 8
#define Tt 512
#define Cc 32
#define Dd 128
#define SCALE 0.08838834764831845f
#define SROW 520  // S row stride in bf16 elems (512 + 8 pad, 16B-aligned)

typedef unsigned int u32;
typedef __hip_bfloat16 bf16;
typedef __attribute__((ext_vector_type(8))) short short8;
typedef __attribute__((ext_vector_type(4))) short short4v;
typedef __attribute__((ext_vector_type(4))) float floatx4;

__device__ __forceinline__ short f2bf(float f) {
    __hip_bfloat16 h = __float2bfloat16(f);
    return *(short*)&h;
}
__device__ __forceinline__ float bf2f(short s) {
    return __uint_as_float(((u32)(unsigned short)s) << 16);
}

// ---------------- Kernel 0: W f32 -> bf16 ----------------
__global__ __launch_bounds__(256)
void k_wconv(const float* __restrict__ wq, const float* __restrict__ wk,
             const float* __restrict__ wv, short* __restrict__ Wb)
{
    int g = blockIdx.x * 256 + threadIdx.x;
    int mat = g >> 14, rem = g & 16383;
    const float* src = (mat == 0) ? wq : (mat == 1) ? wk : wv;
    Wb[g] = f2bf(src[rem]);
}

// ---------------- Kernel 1: gather + QKV (MFMA) + rotation + q*SCALE -------
// Block = 64 consecutive (b,t,c) rows = 2 tokens x 32 channels (r0-proven
// gather locality). 3-pass restructure: one matrix per pass reusing a
// 64x136 ot buffer -> LDS 34.8 KB (4 blocks/CU vs 2) and 32 (not 96) VGPRs
// of weight frags live at a time. MFMA count unchanged; af re-reads are
// cheap ds_read_b128.
__global__ __launch_bounds__(256, 4)
void k_qkvm(const float* __restrict__ x, const int* __restrict__ xm,
            const int* __restrict__ pos, const float* __restrict__ pe,
            const int* __restrict__ imp, const int* __restrict__ idxc,
            const short* __restrict__ Wb,
            const float* __restrict__ bq, const float* __restrict__ bk,
            const float* __restrict__ bv,
            short* __restrict__ qb, short* __restrict__ kb, short* __restrict__ vb)
{
    const int R0  = blockIdx.x * 64;
    const int b   = R0 >> 14;
    const int t0  = (R0 >> 5) & 511;
    const int tid = threadIdx.x;
    const int w    = tid >> 6;
    const int lane = tid & 63;
    const int quad = lane >> 4;
    const int m    = lane & 15;

    __shared__ short xg[64 * 136];
    __shared__ short ot[64 * 136];

#pragma unroll
    for (int i = 0; i < 8; ++i) {
        int u   = tid + i * 256;
        int row = u >> 5, seg = u & 31;
        int R   = R0 + row;
        int idx = xm[R] ? imp[R >> 5] : idxc[R];
        float4 v = *(const float4*)(x + ((long)(R >> 5) * Cc + idx) * Dd + seg * 4);
        short4v s = {f2bf(v.x), f2bf(v.y), f2bf(v.z), f2bf(v.w)};
        *(short4v*)&xg[row * 136 + seg * 4] = s;
    }

    // pos for this thread's 16 output rows, shared by Q and K passes
    int po[4][4];
#pragma unroll
    for (int rt = 0; rt < 4; ++rt)
#pragma unroll
        for (int r = 0; r < 4; ++r)
            po[rt][r] = pos[R0 + rt * 16 + quad * 4 + r];

    __syncthreads();

#pragma unroll
    for (int mat = 0; mat < 3; ++mat) {
        const float* bp = (mat == 0) ? bq : (mat == 1) ? bk : bv;
        short*       dst = (mat == 0) ? qb : (mat == 1) ? kb : vb;

        short8 wf[2][4];
        float  bias_v[2];
#pragma unroll
        for (int h = 0; h < 2; ++h) {
            int ct = h * 4 + w;
            bias_v[h] = bp[ct * 16 + m];
#pragma unroll
            for (int kk = 0; kk < 4; ++kk)
                wf[h][kk] = *(const short8*)(Wb + ((long)mat * 128 + ct * 16 + m) * 128
                                             + kk * 32 + quad * 8);
        }

#pragma unroll
        for (int rt = 0; rt < 4; ++rt) {
            short8 af[4];
#pragma unroll
            for (int kk = 0; kk < 4; ++kk)
                af[kk] = *(const short8*)&xg[(rt * 16 + m) * 136 + kk * 32 + quad * 8];

            floatx4 acc[2];
            acc[0] = (floatx4){0.f, 0.f, 0.f, 0.f};
            acc[1] = (floatx4){0.f, 0.f, 0.f, 0.f};
#pragma unroll
            for (int kk = 0; kk < 4; ++kk)
#pragma unroll
                for (int h = 0; h < 2; ++h)
                    acc[h] = __builtin_amdgcn_mfma_f32_16x16x32_bf16(af[kk], wf[h][kk], acc[h], 0, 0, 0);

#pragma unroll
            for (int h = 0; h < 2; ++h) {
                int ct = h * 4 + w;
                int d  = ct * 16 + m;
#pragma unroll
                for (int r = 0; r < 4; ++r) {
                    float v = acc[h][r] + bias_v[h];
                    float p = __shfl_xor(v, 1, 64);
                    if (mat < 2) {
                        const float* rp = pe + ((long)po[rt][r] * (Dd / 2) + (d >> 1)) * 2;
                        float r0v = rp[0], r1v = rp[1];
                        v = (d & 1) ? fmaf(p, r1v, v * r0v) : fmaf(v, r0v, -(p * r1v));
                        if (mat == 0) v *= SCALE;
                    }
                    ot[(rt * 16 + quad * 4 + r) * 136 + d] = f2bf(v);
                }
            }
        }
        __syncthreads();

        // writeout this matrix: 256B contiguous per (c, t) row
#pragma unroll
        for (int i = 0; i < 4; ++i) {
            int g = tid + i * 256;
            int n = g >> 4, off = (g & 15) * 8;
            int c = n & 31, tl = n >> 5;
            *(short8*)(dst + (((long)(b * Cc + c) * Tt) + t0 + tl) * Dd + off) =
                *(const short8*)&ot[n * 136 + off];
        }
        __syncthreads();
    }
}

// ---------------- Kernel 1b: V transpose + wk fold ----------------
// XOR swizzle on the 8-elem column groups (bijective per row): the
// transpose-read's Delta-row=8 stride (1088 elems == bank 0 mod 32) was an
// 8-way conflict on every element; swizzle spreads the 8 row-groups over
// banks {0,4,...,28}.
__global__ __launch_bounds__(256)
void k_vt(const short* __restrict__ vb, const int* __restrict__ xm,
          short* __restrict__ vt)
{
    const int head = blockIdx.y;
    const int b    = head >> 5;
    const int c    = head & 31;
    const int t0   = blockIdx.x * 64;
    const int tid  = threadIdx.x;

    __shared__ short tile[64 * 136];
    __shared__ float wks[64];

    if (tid < 64)
        wks[tid] = xm[((long)b * Tt + t0 + tid) * Cc + c] ? (1.0f / Tt) : 1.0f;

    const short* src = vb + ((long)head * Tt + t0) * Dd;
#pragma unroll
    for (int i = 0; i < 4; ++i) {
        int u = tid + i * 256;
        int row = u >> 4, col8 = u & 15;
        int c8 = col8 ^ ((row >> 3) & 7);          // swizzled 16B slot
        *(short8*)&tile[row * 136 + c8 * 8] = *(const short8*)(src + row * Dd + col8 * 8);
    }
    __syncthreads();

    short* dst = vt + (long)head * Dd * Tt + t0;
#pragma unroll
    for (int i = 0; i < 4; ++i) {
        int u = tid + i * 256;
        int d = u >> 3, t8 = (u & 7) * 8;
        int key = u & 7;                           // == ((t8+j)>>3)&7 for j<8
        int cs = ((d >> 3) ^ key) * 8 + (d & 7);
        short8 v;
#pragma unroll
        for (int j = 0; j < 8; ++j)
            v[j] = f2bf(bf2f(tile[(t8 + j) * 136 + cs]) * wks[t8 + j]);
        *(short8*)(dst + (long)d * Tt + t8) = v;
    }
}

// ---------------- Kernel 2: TQ=64, 8-wave MFMA attention + fused LN --------
// Exactly the round-1 version (measured 137 us, FETCH 99 MB): TQ=64,
// 2 blocks/CU, XCD grouping (8 heads x 8 q-tiles per XCD -> 2MB L2 window),
// conflict-free interleaved softmax. r3's reg-prefetch additions spilled to
// scratch (VGPR pinned at 64) and regressed -- removed.
__global__ __launch_bounds__(512, 4)
void k_attn(const short* __restrict__ qb, const short* __restrict__ kbp,
            const short* __restrict__ vtp, const float* __restrict__ x,
            const int* __restrict__ pm,
            const float* __restrict__ lsg, const float* __restrict__ lng,
            const float* __restrict__ lnb, float* __restrict__ out)
{
    const int l    = blockIdx.y * 256 + blockIdx.x;
    const int xcd  = l & 7;
    const int sws  = l >> 3;
    const int hh   = sws & 7;
    const int tl   = (sws >> 3) & 7;
    const int gg   = sws >> 6;
    const int head = xcd + ((gg * 8 + hh) << 3);   // head % 8 == xcd
    const int b    = head >> 5;
    const int c    = head & 31;
    const int qt0  = tl * 64;
    const int tid  = threadIdx.x;
    const int w    = tid >> 6;            // 0..7
    const int lane = tid & 63;
    const int quad = lane >> 4;
    const int m    = lane & 15;

    __shared__ short S[64 * SROW];        // 66.6 KB
    __shared__ u32   pkbits[16];
    __shared__ float rlS[64];
    __shared__ float ps1[8][64];
    __shared__ float ps2[8][64];
    __shared__ float mrs[64][2];

    // ---- p_mask bits for all 512 tokens of this head ----
    {
        bool v = pm[((long)b * Tt + tid) * Cc + c] != 0;
        unsigned long long bal = __ballot(v);
        if (lane == 0) {
            pkbits[w * 2]     = (u32)bal;
            pkbits[w * 2 + 1] = (u32)(bal >> 32);
        }
    }

    // ---- Q A-frags: 4 q-tiles (q pre-scaled by SCALE) ----
    short8 qf[4][4];
#pragma unroll
    for (int qt = 0; qt < 4; ++qt)
#pragma unroll
        for (int kk = 0; kk < 4; ++kk)
            qf[qt][kk] = *(const short8*)(qb + ((long)head * Tt + qt0 + qt * 16 + m) * Dd
                                          + kk * 32 + quad * 8);
    __syncthreads();

    // ---- QK^T: each wave owns k-strip w*16 within 128-chunks ----
    for (int ch = 0; ch < 4; ++ch) {
        int kt = ch * 128 + w * 16 + m;
        const short* kp = kbp + ((long)head * Tt + kt) * Dd + quad * 8;
        floatx4 sc[4];
#pragma unroll
        for (int qt = 0; qt < 4; ++qt) sc[qt] = (floatx4){0.f, 0.f, 0.f, 0.f};
#pragma unroll
        for (int kk = 0; kk < 4; ++kk) {
            short8 bk = *(const short8*)(kp + kk * 32);
#pragma unroll
            for (int qt = 0; qt < 4; ++qt)
                sc[qt] = __builtin_amdgcn_mfma_f32_16x16x32_bf16(qf[qt][kk], bk, sc[qt], 0, 0, 0);
        }
        bool masked = (pkbits[kt >> 5] >> (kt & 31)) & 1;
#pragma unroll
        for (int qt = 0; qt < 4; ++qt)
#pragma unroll
            for (int r = 0; r < 4; ++r)
                S[(qt * 16 + quad * 4 + r) * SROW + kt] = f2bf(masked ? -1e30f : sc[qt][r]);
    }
    __syncthreads();

    // ---- softmax: row qi = tid>>3; lane covers cols part*8 + j*64 + e ----
    // (interleaved 8-elem blocks: 128B part-stride was an 8-way bank
    //  conflict; this mapping spreads each phase over all 32 banks.)
    {
        int qi = tid >> 3, part = tid & 7;
        short* rowp = &S[qi * SROW + part * 8];
        short8 sv[8];
#pragma unroll
        for (int j = 0; j < 8; ++j) sv[j] = *(short8*)&rowp[j * 64];
        float mx = -1e30f;
#pragma unroll
        for (int j = 0; j < 8; ++j)
#pragma unroll
            for (int e = 0; e < 8; ++e) mx = fmaxf(mx, bf2f(sv[j][e]));
        mx = fmaxf(mx, __shfl_xor(mx, 1, 64));
        mx = fmaxf(mx, __shfl_xor(mx, 2, 64));
        mx = fmaxf(mx, __shfl_xor(mx, 4, 64));
        float lsum = 0.f;
#pragma unroll
        for (int j = 0; j < 8; ++j)
#pragma unroll
            for (int e = 0; e < 8; ++e) {
                float s = bf2f(sv[j][e]);
                float ex = (s <= -1e29f) ? 0.f : __expf(s - mx);
                sv[j][e] = f2bf(ex);
                lsum += ex;
            }
#pragma unroll
        for (int j = 0; j < 8; ++j) *(short8*)&rowp[j * 64] = sv[j];
        lsum += __shfl_xor(lsum, 1, 64);
        lsum += __shfl_xor(lsum, 2, 64);
        lsum += __shfl_xor(lsum, 4, 64);
        if (part == 0) {
            int t = qt0 + qi;
            bool qmask = (pkbits[t >> 5] >> (t & 31)) & 1;
            rlS[qi] = (lsum > 0.f && !qmask) ? 1.0f / lsum : 0.f;
        }
    }
    __syncthreads();

    // ---- PV: wave owns d-strip w*16..+15; B-frags from Vt global ----
    floatx4 oa[4];
#pragma unroll
    for (int qt = 0; qt < 4; ++qt) oa[qt] = (floatx4){0.f, 0.f, 0.f, 0.f};

    const short* vbase = vtp + (long)head * Dd * Tt + ((long)(w * 16 + m)) * Tt + quad * 8;
    for (int kv = 0; kv < 16; ++kv) {
        short8 bv = *(const short8*)(vbase + kv * 32);
#pragma unroll
        for (int qt = 0; qt < 4; ++qt) {
            short8 ap = *(const short8*)&S[(qt * 16 + m) * SROW + kv * 32 + quad * 8];
            oa[qt] = __builtin_amdgcn_mfma_f32_16x16x32_bf16(ap, bv, oa[qt], 0, 0, 0);
        }
    }

    // ---- epilogue: y = x + ls*(O*rl); LN over d=128 (8-wave partials) ----
    const int d = w * 16 + m;
    const float lg = lsg[d];
    float yv[4][4];
    float s1[4][4], s2[4][4];
#pragma unroll
    for (int qt = 0; qt < 4; ++qt)
#pragma unroll
        for (int r = 0; r < 4; ++r) {
            int row = qt * 16 + quad * 4 + r;
            int t = qt0 + row;
            float val = oa[qt][r] * rlS[row];
            float y = x[(((long)b * Tt + t) * Cc + c) * Dd + d] + lg * val;
            yv[qt][r] = y;
            s1[qt][r] = y;
            s2[qt][r] = y * y;
        }
#pragma unroll
    for (int qt = 0; qt < 4; ++qt)
#pragma unroll
        for (int r = 0; r < 4; ++r) {
            float a = s1[qt][r], bb = s2[qt][r];
            a += __shfl_xor(a, 1, 64); bb += __shfl_xor(bb, 1, 64);
            a += __shfl_xor(a, 2, 64); bb += __shfl_xor(bb, 2, 64);
            a += __shfl_xor(a, 4, 64); bb += __shfl_xor(bb, 4, 64);
            a += __shfl_xor(a, 8, 64); bb += __shfl_xor(bb, 8, 64);
            if (m == 0) {
                ps1[w][qt * 16 + quad * 4 + r] = a;
                ps2[w][qt * 16 + quad * 4 + r] = bb;
            }
        }
    __syncthreads();
    if (tid < 64) {
        float a = 0.f, bb = 0.f;
#pragma unroll
        for (int wv = 0; wv < 8; ++wv) { a += ps1[wv][tid]; bb += ps2[wv][tid]; }
        float mean = a * (1.0f / Dd);
        float var  = bb * (1.0f / Dd) - mean * mean;
        mrs[tid][0] = mean;
        mrs[tid][1] = rsqrtf(var + 1e-5f);
    }
    __syncthreads();

    const float g = lng[d], be = lnb[d];
#pragma unroll
    for (int qt = 0; qt < 4; ++qt)
#pragma unroll
        for (int r = 0; r < 4; ++r) {
            int row = qt * 16 + quad * 4 + r;
            int t = qt0 + row;
            out[(((long)b * Tt + t) * Cc + c) * Dd + d] =
                (yv[qt][r] - mrs[row][0]) * mrs[row][1] * g + be;
        }
}

extern "C" void kernel_launch(void* const* d_in, const int* in_sizes, int n_in,
                              void* d_out, int out_size, void* d_ws, size_t ws_size,
                              hipStream_t stream) {
    const float* x    = (const float*)d_in[0];
    const int* xmask  = (const int*)d_in[1];
    const int* pmask  = (const int*)d_in[2];
    const int* pos    = (const int*)d_in[3];
    const float* pe   = (const float*)d_in[4];
    const int* imp    = (const int*)d_in[5];
    const int* idxc   = (const int*)d_in[6];
    const float* wq_w = (const float*)d_in[7];
    const float* wq_b = (const float*)d_in[8];
    const float* wk_w = (const float*)d_in[9];
    const float* wk_b = (const float*)d_in[10];
    const float* wv_w = (const float*)d_in[11];
    const float* wv_b = (const float*)d_in[12];
    const float* lsg  = (const float*)d_in[13];
    const float* lng  = (const float*)d_in[14];
    const float* lnb  = (const float*)d_in[15];
    float* out = (float*)d_out;

    size_t n = (size_t)Bb * Cc * Tt * Dd;
    short* qb = (short*)d_ws;
    short* kb = qb + n;
    short* vb = kb + n;
    short* vt = vb + n;
    short* Wb = vt + n;

    k_wconv<<<dim3(3 * Dd * Dd / 256), dim3(256), 0, stream>>>(wq_w, wk_w, wv_w, Wb);
    k_qkvm<<<dim3(Bb * Tt * Cc / 64), dim3(256), 0, stream>>>(
        x, xmask, pos, pe, imp, idxc, Wb, wq_b, wk_b, wv_b, qb, kb, vb);
    k_vt<<<dim3(Tt / 64, Bb * Cc), dim3(256), 0, stream>>>(vb, xmask, vt);
    k_attn<<<dim3(256, 8), dim3(512), 0, stream>>>(
        qb, kb, vt, x, pmask, lsg, lng, lnb, out);
}

// Round 5
// 313.520 us; speedup vs baseline: 1.1679x; 1.1679x over previous
//
#include <hip/hip_runtime.h>
#include <hip/hip_bf16.h>

#define Bb 8
#define Tt 512
#define Cc 32
#define Dd 128
#define SCALE 0.08838834764831845f
#define SROW 520  // S row stride in bf16 elems (512 + 8 pad, 16B-aligned)

typedef unsigned int u32;
typedef __hip_bfloat16 bf16;
typedef __attribute__((ext_vector_type(8))) short short8;
typedef __attribute__((ext_vector_type(4))) short short4v;
typedef __attribute__((ext_vector_type(4))) float floatx4;

__device__ __forceinline__ short f2bf(float f) {
    __hip_bfloat16 h = __float2bfloat16(f);
    return *(short*)&h;
}
__device__ __forceinline__ float bf2f(short s) {
    return __uint_as_float(((u32)(unsigned short)s) << 16);
}

// ---------------- Kernel 0: W f32 -> bf16 ----------------
__global__ __launch_bounds__(256)
void k_wconv(const float* __restrict__ wq, const float* __restrict__ wk,
             const float* __restrict__ wv, short* __restrict__ Wb)
{
    int g = blockIdx.x * 256 + threadIdx.x;
    int mat = g >> 14, rem = g & 16383;
    const float* src = (mat == 0) ? wq : (mat == 1) ? wk : wv;
    Wb[g] = f2bf(src[rem]);
}

// ---------------- Kernel 1: gather + QKV (MFMA) + rotation + q*SCALE -------
// r0-exact single-pass version: block = 64 consecutive (b,t,c) rows =
// 2 tokens x 32 channels (gather stays in two 16KB token rows, L1-resident);
// all 3 matrices per pass (2 barriers/block). The r4 3-pass restructure
// (6 barriers, 3x af re-reads) cost ~40us -- reverted.
__global__ __launch_bounds__(256)
void k_qkvm(const float* __restrict__ x, const int* __restrict__ xm,
            const int* __restrict__ pos, const float* __restrict__ pe,
            const int* __restrict__ imp, const int* __restrict__ idxc,
            const short* __restrict__ Wb,
            const float* __restrict__ bq, const float* __restrict__ bk,
            const float* __restrict__ bv,
            short* __restrict__ qb, short* __restrict__ kb, short* __restrict__ vb)
{
    const int R0  = blockIdx.x * 64;
    const int b   = R0 >> 14;
    const int t0  = (R0 >> 5) & 511;
    const int tid = threadIdx.x;
    const int w    = tid >> 6;
    const int lane = tid & 63;
    const int quad = lane >> 4;
    const int m    = lane & 15;

    __shared__ short xg[64 * 136];
    __shared__ short ot[64 * 392];

#pragma unroll
    for (int i = 0; i < 8; ++i) {
        int u   = tid + i * 256;
        int row = u >> 5, seg = u & 31;
        int R   = R0 + row;
        int idx = xm[R] ? imp[R >> 5] : idxc[R];
        float4 v = *(const float4*)(x + ((long)(R >> 5) * Cc + idx) * Dd + seg * 4);
        short4v s = {f2bf(v.x), f2bf(v.y), f2bf(v.z), f2bf(v.w)};
        *(short4v*)&xg[row * 136 + seg * 4] = s;
    }

    short8 wf[6][4];
    float  bias_v[6];
#pragma unroll
    for (int mat = 0; mat < 3; ++mat) {
        const float* bp = (mat == 0) ? bq : (mat == 1) ? bk : bv;
#pragma unroll
        for (int h = 0; h < 2; ++h) {
            int sl = mat * 2 + h;
            int ct = h * 4 + w;
            bias_v[sl] = bp[ct * 16 + m];
#pragma unroll
            for (int kk = 0; kk < 4; ++kk)
                wf[sl][kk] = *(const short8*)(Wb + ((long)mat * 128 + ct * 16 + m) * 128
                                              + kk * 32 + quad * 8);
        }
    }
    __syncthreads();

    for (int rt = 0; rt < 4; ++rt) {
        short8 af[4];
#pragma unroll
        for (int kk = 0; kk < 4; ++kk)
            af[kk] = *(const short8*)&xg[(rt * 16 + m) * 136 + kk * 32 + quad * 8];

        floatx4 acc[6];
#pragma unroll
        for (int sl = 0; sl < 6; ++sl) acc[sl] = (floatx4){0.f, 0.f, 0.f, 0.f};
#pragma unroll
        for (int kk = 0; kk < 4; ++kk)
#pragma unroll
            for (int sl = 0; sl < 6; ++sl)
                acc[sl] = __builtin_amdgcn_mfma_f32_16x16x32_bf16(af[kk], wf[sl][kk], acc[sl], 0, 0, 0);

        int po[4];
#pragma unroll
        for (int r = 0; r < 4; ++r) po[r] = pos[R0 + rt * 16 + quad * 4 + r];

#pragma unroll
        for (int sl = 0; sl < 6; ++sl) {
            int mat = sl >> 1;
            int ct  = (sl & 1) * 4 + w;
            int d   = ct * 16 + m;
#pragma unroll
            for (int r = 0; r < 4; ++r) {
                float v = acc[sl][r] + bias_v[sl];
                float p = __shfl_xor(v, 1, 64);
                if (mat < 2) {
                    const float* rp = pe + ((long)po[r] * (Dd / 2) + (d >> 1)) * 2;
                    float r0 = rp[0], r1 = rp[1];
                    v = (d & 1) ? fmaf(p, r1, v * r0) : fmaf(v, r0, -(p * r1));
                    if (mat == 0) v *= SCALE;
                }
                ot[(rt * 16 + quad * 4 + r) * 392 + mat * 128 + d] = f2bf(v);
            }
        }
    }
    __syncthreads();

    short* const mats[3] = {qb, kb, vb};
#pragma unroll
    for (int mat = 0; mat < 3; ++mat) {
        short* dst = mats[mat];
#pragma unroll
        for (int i = 0; i < 4; ++i) {
            int g = tid + i * 256;
            int n = g >> 4, off = (g & 15) * 8;
            int c = n & 31, tl = n >> 5;
            *(short8*)(dst + (((long)(b * Cc + c) * Tt) + t0 + tl) * Dd + off) =
                *(const short8*)&ot[n * 392 + mat * 128 + off];
        }
    }
}

// ---------------- Kernel 1b: V transpose + wk fold ----------------
// r0 structure + XOR swizzle on the 8-elem column groups (bijective per
// row). r0's transpose read had lanes 0-7 at t8 multiples of 8 -> bank
// offset t8*68 == 0 mod 32 -> true 8-way conflict on 64 scalar reads/lane.
// Swizzle spreads the 8 t8-groups over 8 distinct banks (verified r4,
// correctness-proven).
__global__ __launch_bounds__(256)
void k_vt(const short* __restrict__ vb, const int* __restrict__ xm,
          short* __restrict__ vt)
{
    const int head = blockIdx.y;
    const int b    = head >> 5;
    const int c    = head & 31;
    const int t0   = blockIdx.x * 64;
    const int tid  = threadIdx.x;

    __shared__ short tile[64 * 136];
    __shared__ float wks[64];

    if (tid < 64)
        wks[tid] = xm[((long)b * Tt + t0 + tid) * Cc + c] ? (1.0f / Tt) : 1.0f;

    const short* src = vb + ((long)head * Tt + t0) * Dd;
#pragma unroll
    for (int i = 0; i < 4; ++i) {
        int u = tid + i * 256;
        int row = u >> 4, col8 = u & 15;
        int c8 = col8 ^ ((row >> 3) & 7);          // swizzled 16B slot
        *(short8*)&tile[row * 136 + c8 * 8] = *(const short8*)(src + row * Dd + col8 * 8);
    }
    __syncthreads();

    short* dst = vt + (long)head * Dd * Tt + t0;
#pragma unroll
    for (int i = 0; i < 4; ++i) {
        int u = tid + i * 256;
        int d = u >> 3, t8 = (u & 7) * 8;
        int key = u & 7;                           // == ((t8+j)>>3)&7 for j<8
        int cs = ((d >> 3) ^ key) * 8 + (d & 7);
        short8 v;
#pragma unroll
        for (int j = 0; j < 8; ++j)
            v[j] = f2bf(bf2f(tile[(t8 + j) * 136 + cs]) * wks[t8 + j]);
        *(short8*)(dst + (long)d * Tt + t8) = v;
    }
}

// ---------------- Kernel 2: TQ=64, 8-wave MFMA attention + fused LN --------
// r1-exact (measured 137-141 us across three rounds): TQ=64, 2 blocks/CU,
// XCD grouping (8 heads x 8 q-tiles per XCD -> 2MB L2 window, FETCH ~100MB),
// conflict-free interleaved softmax. Reg-prefetch (r3) spilled; TQ=32 (r2)
// doubled traffic -- both rejected.
__global__ __launch_bounds__(512, 4)
void k_attn(const short* __restrict__ qb, const short* __restrict__ kbp,
            const short* __restrict__ vtp, const float* __restrict__ x,
            const int* __restrict__ pm,
            const float* __restrict__ lsg, const float* __restrict__ lng,
            const float* __restrict__ lnb, float* __restrict__ out)
{
    const int l    = blockIdx.y * 256 + blockIdx.x;
    const int xcd  = l & 7;
    const int sws  = l >> 3;
    const int hh   = sws & 7;
    const int tl   = (sws >> 3) & 7;
    const int gg   = sws >> 6;
    const int head = xcd + ((gg * 8 + hh) << 3);   // head % 8 == xcd
    const int b    = head >> 5;
    const int c    = head & 31;
    const int qt0  = tl * 64;
    const int tid  = threadIdx.x;
    const int w    = tid >> 6;            // 0..7
    const int lane = tid & 63;
    const int quad = lane >> 4;
    const int m    = lane & 15;

    __shared__ short S[64 * SROW];        // 66.6 KB
    __shared__ u32   pkbits[16];
    __shared__ float rlS[64];
    __shared__ float ps1[8][64];
    __shared__ float ps2[8][64];
    __shared__ float mrs[64][2];

    // ---- p_mask bits for all 512 tokens of this head ----
    {
        bool v = pm[((long)b * Tt + tid) * Cc + c] != 0;
        unsigned long long bal = __ballot(v);
        if (lane == 0) {
            pkbits[w * 2]     = (u32)bal;
            pkbits[w * 2 + 1] = (u32)(bal >> 32);
        }
    }

    // ---- Q A-frags: 4 q-tiles (q pre-scaled by SCALE) ----
    short8 qf[4][4];
#pragma unroll
    for (int qt = 0; qt < 4; ++qt)
#pragma unroll
        for (int kk = 0; kk < 4; ++kk)
            qf[qt][kk] = *(const short8*)(qb + ((long)head * Tt + qt0 + qt * 16 + m) * Dd
                                          + kk * 32 + quad * 8);
    __syncthreads();

    // ---- QK^T: each wave owns k-strip w*16 within 128-chunks ----
    for (int ch = 0; ch < 4; ++ch) {
        int kt = ch * 128 + w * 16 + m;
        const short* kp = kbp + ((long)head * Tt + kt) * Dd + quad * 8;
        floatx4 sc[4];
#pragma unroll
        for (int qt = 0; qt < 4; ++qt) sc[qt] = (floatx4){0.f, 0.f, 0.f, 0.f};
#pragma unroll
        for (int kk = 0; kk < 4; ++kk) {
            short8 bk = *(const short8*)(kp + kk * 32);
#pragma unroll
            for (int qt = 0; qt < 4; ++qt)
                sc[qt] = __builtin_amdgcn_mfma_f32_16x16x32_bf16(qf[qt][kk], bk, sc[qt], 0, 0, 0);
        }
        bool masked = (pkbits[kt >> 5] >> (kt & 31)) & 1;
#pragma unroll
        for (int qt = 0; qt < 4; ++qt)
#pragma unroll
            for (int r = 0; r < 4; ++r)
                S[(qt * 16 + quad * 4 + r) * SROW + kt] = f2bf(masked ? -1e30f : sc[qt][r]);
    }
    __syncthreads();

    // ---- softmax: row qi = tid>>3; lane covers cols part*8 + j*64 + e ----
    // (interleaved 8-elem blocks: 128B part-stride was an 8-way bank
    //  conflict; this mapping spreads each phase over all 32 banks.)
    {
        int qi = tid >> 3, part = tid & 7;
        short* rowp = &S[qi * SROW + part * 8];
        short8 sv[8];
#pragma unroll
        for (int j = 0; j < 8; ++j) sv[j] = *(short8*)&rowp[j * 64];
        float mx = -1e30f;
#pragma unroll
        for (int j = 0; j < 8; ++j)
#pragma unroll
            for (int e = 0; e < 8; ++e) mx = fmaxf(mx, bf2f(sv[j][e]));
        mx = fmaxf(mx, __shfl_xor(mx, 1, 64));
        mx = fmaxf(mx, __shfl_xor(mx, 2, 64));
        mx = fmaxf(mx, __shfl_xor(mx, 4, 64));
        float lsum = 0.f;
#pragma unroll
        for (int j = 0; j < 8; ++j)
#pragma unroll
            for (int e = 0; e < 8; ++e) {
                float s = bf2f(sv[j][e]);
                float ex = (s <= -1e29f) ? 0.f : __expf(s - mx);
                sv[j][e] = f2bf(ex);
                lsum += ex;
            }
#pragma unroll
        for (int j = 0; j < 8; ++j) *(short8*)&rowp[j * 64] = sv[j];
        lsum += __shfl_xor(lsum, 1, 64);
        lsum += __shfl_xor(lsum, 2, 64);
        lsum += __shfl_xor(lsum, 4, 64);
        if (part == 0) {
            int t = qt0 + qi;
            bool qmask = (pkbits[t >> 5] >> (t & 31)) & 1;
            rlS[qi] = (lsum > 0.f && !qmask) ? 1.0f / lsum : 0.f;
        }
    }
    __syncthreads();

    // ---- PV: wave owns d-strip w*16..+15; B-frags from Vt global ----
    floatx4 oa[4];
#pragma unroll
    for (int qt = 0; qt < 4; ++qt) oa[qt] = (floatx4){0.f, 0.f, 0.f, 0.f};

    const short* vbase = vtp + (long)head * Dd * Tt + ((long)(w * 16 + m)) * Tt + quad * 8;
    for (int kv = 0; kv < 16; ++kv) {
        short8 bv = *(const short8*)(vbase + kv * 32);
#pragma unroll
        for (int qt = 0; qt < 4; ++qt) {
            short8 ap = *(const short8*)&S[(qt * 16 + m) * SROW + kv * 32 + quad * 8];
            oa[qt] = __builtin_amdgcn_mfma_f32_16x16x32_bf16(ap, bv, oa[qt], 0, 0, 0);
        }
    }

    // ---- epilogue: y = x + ls*(O*rl); LN over d=128 (8-wave partials) ----
    const int d = w * 16 + m;
    const float lg = lsg[d];
    float yv[4][4];
    float s1[4][4], s2[4][4];
#pragma unroll
    for (int qt = 0; qt < 4; ++qt)
#pragma unroll
        for (int r = 0; r < 4; ++r) {
            int row = qt * 16 + quad * 4 + r;
            int t = qt0 + row;
            float val = oa[qt][r] * rlS[row];
            float y = x[(((long)b * Tt + t) * Cc + c) * Dd + d] + lg * val;
            yv[qt][r] = y;
            s1[qt][r] = y;
            s2[qt][r] = y * y;
        }
#pragma unroll
    for (int qt = 0; qt < 4; ++qt)
#pragma unroll
        for (int r = 0; r < 4; ++r) {
            float a = s1[qt][r], bb = s2[qt][r];
            a += __shfl_xor(a, 1, 64); bb += __shfl_xor(bb, 1, 64);
            a += __shfl_xor(a, 2, 64); bb += __shfl_xor(bb, 2, 64);
            a += __shfl_xor(a, 4, 64); bb += __shfl_xor(bb, 4, 64);
            a += __shfl_xor(a, 8, 64); bb += __shfl_xor(bb, 8, 64);
            if (m == 0) {
                ps1[w][qt * 16 + quad * 4 + r] = a;
                ps2[w][qt * 16 + quad * 4 + r] = bb;
            }
        }
    __syncthreads();
    if (tid < 64) {
        float a = 0.f, bb = 0.f;
#pragma unroll
        for (int wv = 0; wv < 8; ++wv) { a += ps1[wv][tid]; bb += ps2[wv][tid]; }
        float mean = a * (1.0f / Dd);
        float var  = bb * (1.0f / Dd) - mean * mean;
        mrs[tid][0] = mean;
        mrs[tid][1] = rsqrtf(var + 1e-5f);
    }
    __syncthreads();

    const float g = lng[d], be = lnb[d];
#pragma unroll
    for (int qt = 0; qt < 4; ++qt)
#pragma unroll
        for (int r = 0; r < 4; ++r) {
            int row = qt * 16 + quad * 4 + r;
            int t = qt0 + row;
            out[(((long)b * Tt + t) * Cc + c) * Dd + d] =
                (yv[qt][r] - mrs[row][0]) * mrs[row][1] * g + be;
        }
}

extern "C" void kernel_launch(void* const* d_in, const int* in_sizes, int n_in,
                              void* d_out, int out_size, void* d_ws, size_t ws_size,
                              hipStream_t stream) {
    const float* x    = (const float*)d_in[0];
    const int* xmask  = (const int*)d_in[1];
    const int* pmask  = (const int*)d_in[2];
    const int* pos    = (const int*)d_in[3];
    const float* pe   = (const float*)d_in[4];
    const int* imp    = (const int*)d_in[5];
    const int* idxc   = (const int*)d_in[6];
    const float* wq_w = (const float*)d_in[7];
    const float* wq_b = (const float*)d_in[8];
    const float* wk_w = (const float*)d_in[9];
    const float* wk_b = (const float*)d_in[10];
    const float* wv_w = (const float*)d_in[11];
    const float* wv_b = (const float*)d_in[12];
    const float* lsg  = (const float*)d_in[13];
    const float* lng  = (const float*)d_in[14];
    const float* lnb  = (const float*)d_in[15];
    float* out = (float*)d_out;

    size_t n = (size_t)Bb * Cc * Tt * Dd;
    short* qb = (short*)d_ws;
    short* kb = qb + n;
    short* vb = kb + n;
    short* vt = vb + n;
    short* Wb = vt + n;

    k_wconv<<<dim3(3 * Dd * Dd / 256), dim3(256), 0, stream>>>(wq_w, wk_w, wv_w, Wb);
    k_qkvm<<<dim3(Bb * Tt * Cc / 64), dim3(256), 0, stream>>>(
        x, xmask, pos, pe, imp, idxc, Wb, wq_b, wk_b, wv_b, qb, kb, vb);
    k_vt<<<dim3(Tt / 64, Bb * Cc), dim3(256), 0, stream>>>(vb, xmask, vt);
    k_attn<<<dim3(256, 8), dim3(512), 0, stream>>>(
        qb, kb, vt, x, pmask, lsg, lng, lnb, out);
}